// Round 4
// baseline (2260.503 us; speedup 1.0000x reference)
//
#include <hip/hip_runtime.h>

// RoIAlign matching jax.image.scale_and_translate(method="linear", antialias=True)
// feature_map: [512][512][64] f32, boxes: [512][4] f32 (cx,cy,w,h), out: [512][32][32][64] f32
// Separable: per (box,row) x-resize once (LDS-staged row), then y-accumulate into registers.

#define H_IN 512
#define W_IN 512
#define CH   64
#define NB   512
#define OW   32
#define WSTRIDE 33   // weights per (box,dim,o)
#define TAPS_MAX 33  // ks <= 16 -> taps <= 2*ks+1 = 33
#define COLS_MAX 512 // x-union of 32 ox windows, clamped to [0,512)

// ---------------------------------------------------------------------------
// Kernel 1: per (box, dim, o) tap table (unchanged — verified correct R1/R3).
// ---------------------------------------------------------------------------
__global__ __launch_bounds__(256) void roi_weights(const float* __restrict__ boxes,
                                                   float* __restrict__ wTab,
                                                   int* __restrict__ meta) {
    int tid = blockIdx.x * blockDim.x + threadIdx.x;
    if (tid >= NB * 2 * 32) return;
    int o   = tid & 31;
    int dim = (tid >> 5) & 1;   // 0 = y, 1 = x
    int b   = tid >> 6;

    float cx = boxes[b * 4 + 0];
    float cy = boxes[b * 4 + 1];
    float bw = boxes[b * 4 + 2];
    float bh = boxes[b * 4 + 3];
    float cc = dim ? cx : cy;
    float sz = dim ? bw : bh;
    float lo = cc - sz * 0.5f;        // x0/y0 use PRE-clamp size (matches ref)
    sz = fmaxf(sz, 1e-6f);

    float scale = (float)OW / (sz * (float)W_IN);
    float inv   = 1.0f / scale;
    float trans = (-lo * (float)OW) / sz;
    float s     = ((float)o + 0.5f) * inv - trans * inv - 0.5f;
    float ks    = fmaxf(inv, 1.0f);

    int i_lo = max((int)ceilf(s - ks), 0);
    int i_hi = min((int)floorf(s + ks), W_IN - 1);
    int cnt  = i_hi - i_lo + 1;
    if (cnt < 0) cnt = 0;
    if (cnt > TAPS_MAX) cnt = TAPS_MAX;

    float sum = 0.0f;
    for (int k = 0; k < cnt; ++k) {
        float x = fabsf(s - (float)(i_lo + k)) / ks;
        sum += fmaxf(0.0f, 1.0f - x);
    }
    bool ok = (sum > 1.1920929e-4f) && (s >= -0.5f) && (s <= (float)W_IN - 0.5f);

    float* wout = wTab + ((size_t)(dim * NB + b) * 32 + o) * WSTRIDE;
    for (int k = 0; k < TAPS_MAX; ++k) {
        float w = 0.0f;
        if (ok && k < cnt) {
            float x = fabsf(s - (float)(i_lo + k)) / ks;
            w = fmaxf(0.0f, 1.0f - x) / sum;
        }
        wout[k] = w;
    }
    int* m = meta + ((size_t)(dim * NB + b) * 32 + o) * 2;
    m[0] = i_lo;
    m[1] = ok ? cnt : 0;
}

// direct global->LDS, 16B per lane; LDS dest = uniform base + laneid*16
__device__ __forceinline__ void gload16(const float* src, float* ldsDst) {
    __builtin_amdgcn_global_load_lds((const __attribute__((address_space(1))) void*)src,
                                     (__attribute__((address_space(3))) void*)ldsDst, 16, 0, 0);
}

// ---------------------------------------------------------------------------
// Kernel 2: separable RoI resize.
// block = (box, oy-half, ch-quarter); grid 4096.
// bid mapping: xcd = bid&7, sub = (bid>>3)&7, q = bid>>6; box = q*8+xcd ->
// a box's 8 sub-blocks are dispatched within 64 bids AND land on one XCD
// (round-robin) -> concurrent, disjoint-byte reads of the same fm region.
// Threads: ox = t>>3 (32), cp = t&7 -> channels ch0+2*cp, +1.
// Per row: stage next row [cols][16ch] via global_load_lds (double-buffered),
// x-pass from LDS (ds_read_b64), y-accum into 32 register accumulators with
// statically unrolled oy loop (wave-uniform predicate -> cheap branch).
// ---------------------------------------------------------------------------
__global__ __launch_bounds__(256) void roi_sep(const float* __restrict__ fm,
                                               const float* __restrict__ wTab,
                                               const int* __restrict__ meta,
                                               float* __restrict__ out) {
    __shared__ float sBuf[2][COLS_MAX * 16];     // 64 KB: [col][16ch], linear for global_load_lds
    __shared__ float sWx[32 * WSTRIDE];          // 4224 B
    __shared__ float sWy[16 * WSTRIDE];          // 2112 B
    __shared__ int   sMx[64];                    // (ix0, cntx) per ox
    __shared__ int   sMyLC[16];                  // i_lo | cnt<<16 per oy
    __shared__ int   sU[4];                      // u0, cu, xu0, cux

    int bid = blockIdx.x;
    int box = ((bid >> 6) << 3) + (bid & 7);
    int sub = (bid >> 3) & 7;
    int oyh = sub >> 2;          // 0..1
    int chh = sub & 3;           // 0..3
    int ch0 = chh * 16;
    int oy0 = oyh * 16;
    int t   = threadIdx.x;

    const float* wxsrc = wTab + (size_t)(NB + box) * 32 * WSTRIDE;
    for (int i = t; i < 32 * WSTRIDE; i += 256) sWx[i] = wxsrc[i];
    const float* wysrc = wTab + ((size_t)box * 32 + oy0) * WSTRIDE;
    for (int i = t; i < 16 * WSTRIDE; i += 256) sWy[i] = wysrc[i];
    if (t < 64) sMx[t] = meta[(size_t)(NB + box) * 64 + t];
    if (t < 16) {
        int lo = meta[((size_t)box * 32 + oy0 + t) * 2];
        int cn = meta[((size_t)box * 32 + oy0 + t) * 2 + 1];
        sMyLC[t] = (lo & 0xffff) | (cn << 16);
    }
    __syncthreads();
    if (t == 0) {
        int lo = 0x7fffffff, hi = -1;
        for (int k = 0; k < 16; ++k) {
            int lc = sMyLC[k], c = lc >> 16;
            if (c > 0) { int l = lc & 0xffff; lo = min(lo, l); hi = max(hi, l + c); }
        }
        sU[0] = (hi > lo) ? lo : 0;
        sU[1] = (hi > lo) ? (hi - lo) : 0;
        int xlo = 0x7fffffff, xhi = -1;
        for (int k = 0; k < 32; ++k) {
            int c = sMx[2 * k + 1];
            if (c > 0) { int l = sMx[2 * k]; xlo = min(xlo, l); xhi = max(xhi, l + c); }
        }
        sU[2] = (xhi > xlo) ? xlo : 0;
        int cux = (xhi > xlo) ? (xhi - xlo) : 0;
        sU[3] = (cux > COLS_MAX) ? COLS_MAX : cux;
    }
    __syncthreads();
    int u0 = sU[0], cu = sU[1], xu0 = sU[2], cux = sU[3];

    int wave = t >> 6, lane = t & 63;
    int ox = t >> 3, cp = t & 7;
    int ix0rel = sMx[2 * ox] - xu0;   // >= 0 whenever cntx > 0
    int cntx   = sMx[2 * ox + 1];

    float accA[16], accB[16];
    #pragma unroll
    for (int k = 0; k < 16; ++k) { accA[k] = 0.f; accB[k] = 0.f; }

    // prologue: stage row 0 into buf 0
    if (cu > 0) {
        int iy = u0;
        for (int c0w = wave * 16; c0w < cux; c0w += 64) {
            int col = c0w + (lane >> 2);
            if (col < cux) {
                const float* src = fm + ((size_t)iy * W_IN + xu0 + col) * CH + ch0 + (lane & 3) * 4;
                gload16(src, &sBuf[0][c0w * 16]);
            }
        }
        __syncthreads();   // drains vmcnt -> buf0 ready
    }

    int cur = 0;
    for (int r = 0; r < cu; ++r) {
        // issue stage of row r+1 into the other buffer (latency hides under compute)
        if (r + 1 < cu) {
            int iy = u0 + r + 1;
            float* dst = &sBuf[cur ^ 1][0];
            for (int c0w = wave * 16; c0w < cux; c0w += 64) {
                int col = c0w + (lane >> 2);
                if (col < cux) {
                    const float* src = fm + ((size_t)iy * W_IN + xu0 + col) * CH + ch0 + (lane & 3) * 4;
                    gload16(src, dst + c0w * 16);
                }
            }
        }

        // x-pass: xrow for this (ox, 2ch) from current buffer
        const float* wxp = &sWx[ox * WSTRIDE];
        const float* bp  = &sBuf[cur][0] + ix0rel * 16 + cp * 2;
        float xa = 0.f, xb = 0.f;
        for (int tx = 0; tx < cntx; ++tx) {
            float w = wxp[tx];
            float2 v = *(const float2*)bp;
            xa = fmaf(w, v.x, xa);
            xb = fmaf(w, v.y, xb);
            bp += 16;
        }

        // y-accumulate: statically unrolled, wave-uniform predicate per oy
        int iy = u0 + r;
        #pragma unroll
        for (int oy = 0; oy < 16; ++oy) {
            int lc = sMyLC[oy];
            int rr = iy - (lc & 0xffff);
            if ((unsigned)rr < (unsigned)(lc >> 16)) {
                float w = sWy[oy * WSTRIDE + rr];
                accA[oy] = fmaf(w, xa, accA[oy]);
                accB[oy] = fmaf(w, xb, accB[oy]);
            }
        }

        __syncthreads();   // all readers done with buf[cur]; stage of r+1 drained
        cur ^= 1;
    }

    // store: 16 oy x float2 per thread (zeros where no coverage — matches ref)
    #pragma unroll
    for (int oy = 0; oy < 16; ++oy) {
        float* op = out + (((size_t)box * 32 + oy0 + oy) * 32 + ox) * CH + ch0 + cp * 2;
        *(float2*)op = make_float2(accA[oy], accB[oy]);
    }
}

extern "C" void kernel_launch(void* const* d_in, const int* in_sizes, int n_in,
                              void* d_out, int out_size, void* d_ws, size_t ws_size,
                              hipStream_t stream) {
    const float* fm    = (const float*)d_in[0];
    const float* boxes = (const float*)d_in[1];
    // d_in[2] = output_width (==32), hardcoded.

    float* wTab = (float*)d_ws;                                   // 2*512*32*33 f32 = 4.33 MB
    int*   meta = (int*)((char*)d_ws + (size_t)2 * NB * 32 * WSTRIDE * sizeof(float)); // 512 KB

    roi_weights<<<(NB * 2 * 32 + 255) / 256, 256, 0, stream>>>(boxes, wTab, meta);
    roi_sep<<<NB * 8, 256, 0, stream>>>(fm, wTab, meta, (float*)d_out);
}

// Round 5
// 1535.865 us; speedup vs baseline: 1.4718x; 1.4718x over previous
//
#include <hip/hip_runtime.h>

// RoIAlign matching jax.image.scale_and_translate(method="linear", antialias=True)
// feature_map: [512][512][64] f32, boxes: [512][4] f32 (cx,cy,w,h), out: [512][32][32][64] f32
// Separable: per (box,row) x-resize once (LDS-staged row, chunk-8 pipelined), y-accumulate in regs.

#define H_IN 512
#define W_IN 512
#define CH   64
#define NB   512
#define OW   32
#define WSTRIDE 33    // weights per (box,dim,o) in the global table
#define WXS     40    // padded x-weight stride in LDS (zeros at [cnt,40))
#define TAPS_MAX 33   // ks <= 16 -> taps <= 2*ks+1 = 33
#define COLS_MAX 512
#define COLS_PAD 528  // +16 pad cols (zeroed) for chunk-8 overread

// ---------------------------------------------------------------------------
// Kernel 1: per (box, dim, o) tap table (unchanged — verified correct R1-R4).
// ---------------------------------------------------------------------------
__global__ __launch_bounds__(256) void roi_weights(const float* __restrict__ boxes,
                                                   float* __restrict__ wTab,
                                                   int* __restrict__ meta) {
    int tid = blockIdx.x * blockDim.x + threadIdx.x;
    if (tid >= NB * 2 * 32) return;
    int o   = tid & 31;
    int dim = (tid >> 5) & 1;   // 0 = y, 1 = x
    int b   = tid >> 6;

    float cx = boxes[b * 4 + 0];
    float cy = boxes[b * 4 + 1];
    float bw = boxes[b * 4 + 2];
    float bh = boxes[b * 4 + 3];
    float cc = dim ? cx : cy;
    float sz = dim ? bw : bh;
    float lo = cc - sz * 0.5f;        // x0/y0 use PRE-clamp size (matches ref)
    sz = fmaxf(sz, 1e-6f);

    float scale = (float)OW / (sz * (float)W_IN);
    float inv   = 1.0f / scale;
    float trans = (-lo * (float)OW) / sz;
    float s     = ((float)o + 0.5f) * inv - trans * inv - 0.5f;
    float ks    = fmaxf(inv, 1.0f);

    int i_lo = max((int)ceilf(s - ks), 0);
    int i_hi = min((int)floorf(s + ks), W_IN - 1);
    int cnt  = i_hi - i_lo + 1;
    if (cnt < 0) cnt = 0;
    if (cnt > TAPS_MAX) cnt = TAPS_MAX;

    float sum = 0.0f;
    for (int k = 0; k < cnt; ++k) {
        float x = fabsf(s - (float)(i_lo + k)) / ks;
        sum += fmaxf(0.0f, 1.0f - x);
    }
    bool ok = (sum > 1.1920929e-4f) && (s >= -0.5f) && (s <= (float)W_IN - 0.5f);

    float* wout = wTab + ((size_t)(dim * NB + b) * 32 + o) * WSTRIDE;
    for (int k = 0; k < TAPS_MAX; ++k) {
        float w = 0.0f;
        if (ok && k < cnt) {
            float x = fabsf(s - (float)(i_lo + k)) / ks;
            w = fmaxf(0.0f, 1.0f - x) / sum;
        }
        wout[k] = w;
    }
    int* m = meta + ((size_t)(dim * NB + b) * 32 + o) * 2;
    m[0] = i_lo;
    m[1] = ok ? cnt : 0;
}

// direct global->LDS, 16B per lane; LDS dest = wave-uniform base + laneid*16
__device__ __forceinline__ void gload16(const float* src, float* ldsDst) {
    __builtin_amdgcn_global_load_lds((const __attribute__((address_space(1))) void*)src,
                                     (__attribute__((address_space(3))) void*)ldsDst, 16, 0, 0);
}

// ---------------------------------------------------------------------------
// Kernel 2: separable RoI resize.
// block = (box, oy-half, ch-quarter); grid 4096; bid: xcd=bid&7, sub=(bid>>3)&7,
// box=((bid>>6)<<3)+(bid&7) -> a box's 8 sub-blocks co-dispatch on one XCD.
// Threads: ox = t>>3 (32), cp = t&7 -> channels ch0+2*cp,+1.
// Per row: stage next row [col][16ch] via global_load_lds (double-buffered,
// issued BEFORE compute -> latency hides), x-pass in chunks of 8 taps with a
// statically-indexed float2 reg array (8 LDS reads in flight), y-accum with
// hoisted (lo,cnt) regs, single __syncthreads per row.
// ---------------------------------------------------------------------------
__global__ __launch_bounds__(256) void roi_sep3(const float* __restrict__ fm,
                                                const float* __restrict__ wTab,
                                                const int* __restrict__ meta,
                                                float* __restrict__ out) {
    __shared__ float sBuf[2][COLS_PAD * 16];     // 67.6 KB
    __shared__ float sWx[32 * WXS];              // 5.1 KB, zero-padded taps
    __shared__ float sWy[16 * WSTRIDE];          // 2.1 KB
    __shared__ int   sMx[64];                    // (ix0, cntx) per ox
    __shared__ int   sMyLC[16];                  // i_lo | cnt<<16 per oy
    __shared__ int   sU[4];                      // u0, cu, xu0, cux

    int bid = blockIdx.x;
    int box = ((bid >> 6) << 3) + (bid & 7);
    int sub = (bid >> 3) & 7;
    int ch0 = (sub & 3) * 16;
    int oy0 = (sub >> 2) * 16;
    int t   = threadIdx.x;

    const float* wxsrc = wTab + (size_t)(NB + box) * 32 * WSTRIDE;
    for (int i = t; i < 32 * WXS; i += 256) {
        int o = i / WXS, k = i - o * WXS;
        sWx[i] = (k < WSTRIDE) ? wxsrc[o * WSTRIDE + k] : 0.0f;
    }
    const float* wysrc = wTab + ((size_t)box * 32 + oy0) * WSTRIDE;
    for (int i = t; i < 16 * WSTRIDE; i += 256) sWy[i] = wysrc[i];
    if (t < 64) sMx[t] = meta[(size_t)(NB + box) * 64 + t];
    if (t < 16) {
        int lo = meta[((size_t)box * 32 + oy0 + t) * 2];
        int cn = meta[((size_t)box * 32 + oy0 + t) * 2 + 1];
        sMyLC[t] = (lo & 0xffff) | (cn << 16);
    }
    __syncthreads();
    if (t == 0) {
        int lo = 0x7fffffff, hi = -1;
        for (int k = 0; k < 16; ++k) {
            int lc = sMyLC[k], c = lc >> 16;
            if (c > 0) { int l = lc & 0xffff; lo = min(lo, l); hi = max(hi, l + c); }
        }
        sU[0] = (hi > lo) ? lo : 0;
        sU[1] = (hi > lo) ? (hi - lo) : 0;
        int xlo = 0x7fffffff, xhi = -1;
        for (int k = 0; k < 32; ++k) {
            int c = sMx[2 * k + 1];
            if (c > 0) { int l = sMx[2 * k]; xlo = min(xlo, l); xhi = max(xhi, l + c); }
        }
        sU[2] = (xhi > xlo) ? xlo : 0;
        int cux = (xhi > xlo) ? (xhi - xlo) : 0;
        sU[3] = (cux > COLS_MAX) ? COLS_MAX : cux;
    }
    __syncthreads();
    int u0 = sU[0], cu = sU[1], xu0 = sU[2], cux = sU[3];

    int wave = t >> 6, lane = t & 63;
    int ox = t >> 3, cp = t & 7;
    int ix0rel = max(sMx[2 * ox] - xu0, 0);   // clamp (cnt==0 cols may have lo<xu0)
    int cntx   = sMx[2 * ox + 1];
    int nch    = (cntx + 7) >> 3;             // chunk count (0 if cntx==0)

    // hoist y meta into regs (static idx)
    int myLC[16];
    #pragma unroll
    for (int k = 0; k < 16; ++k) myLC[k] = sMyLC[k];

    float accA[16], accB[16];
    #pragma unroll
    for (int k = 0; k < 16; ++k) { accA[k] = 0.f; accB[k] = 0.f; }

    // zero the pad cols [cux, cux+16) of both buffers once (finite for 0-weight taps)
    for (int i = t; i < 2 * 16 * 16; i += 256) {
        int b = i >> 8, col = (i >> 4) & 15, ch = i & 15;
        sBuf[b][(cux + col) * 16 + ch] = 0.0f;
    }

    // per-lane global source offset: col-in-group = lane>>2, ch-quad = lane&3
    const float* laneSrc = fm + (size_t)(xu0 + (lane >> 2)) * CH + ch0 + (lane & 3) * 4;
    int laneCol = lane >> 2;

    // prologue: stage row 0 into buf 0
    if (cu > 0) {
        const float* rowSrc = laneSrc + (size_t)u0 * (W_IN * CH);
        for (int c0w = wave * 16; c0w < cux; c0w += 64) {
            if (c0w + laneCol < cux) gload16(rowSrc + c0w * CH, &sBuf[0][c0w * 16]);
        }
    }
    __syncthreads();   // pads zeroed + buf0 staged

    int cur = 0;
    for (int r = 0; r < cu; ++r) {
        // issue stage of row r+1 into the other buffer BEFORE compute (overlap)
        if (r + 1 < cu) {
            const float* rowSrc = laneSrc + (size_t)(u0 + r + 1) * (W_IN * CH);
            float* dst = &sBuf[cur ^ 1][0];
            for (int c0w = wave * 16; c0w < cux; c0w += 64) {
                if (c0w + laneCol < cux) gload16(rowSrc + c0w * CH, dst + c0w * 16);
            }
        }

        // x-pass: chunk-8, 8 LDS reads in flight, statically indexed regs
        const float* wxp = &sWx[ox * WXS];
        const float* bp  = &sBuf[cur][0] + ix0rel * 16 + cp * 2;
        float xa = 0.f, xb = 0.f;
        for (int c = 0; c < nch; ++c) {
            float2 v[8];
            #pragma unroll
            for (int k = 0; k < 8; ++k) v[k] = *(const float2*)(bp + k * 16);
            float4 w0 = *(const float4*)(wxp + c * 8);
            float4 w1 = *(const float4*)(wxp + c * 8 + 4);
            xa = fmaf(w0.x, v[0].x, xa); xb = fmaf(w0.x, v[0].y, xb);
            xa = fmaf(w0.y, v[1].x, xa); xb = fmaf(w0.y, v[1].y, xb);
            xa = fmaf(w0.z, v[2].x, xa); xb = fmaf(w0.z, v[2].y, xb);
            xa = fmaf(w0.w, v[3].x, xa); xb = fmaf(w0.w, v[3].y, xb);
            xa = fmaf(w1.x, v[4].x, xa); xb = fmaf(w1.x, v[4].y, xb);
            xa = fmaf(w1.y, v[5].x, xa); xb = fmaf(w1.y, v[5].y, xb);
            xa = fmaf(w1.z, v[6].x, xa); xb = fmaf(w1.z, v[6].y, xb);
            xa = fmaf(w1.w, v[7].x, xa); xb = fmaf(w1.w, v[7].y, xb);
            bp += 128;
        }

        // y-accumulate: statically unrolled, predicate from hoisted regs
        int iy = u0 + r;
        #pragma unroll
        for (int oy = 0; oy < 16; ++oy) {
            int lc = myLC[oy];
            int rr = iy - (lc & 0xffff);
            if ((unsigned)rr < (unsigned)(lc >> 16)) {
                float w = sWy[oy * WSTRIDE + rr];
                accA[oy] = fmaf(w, xa, accA[oy]);
                accB[oy] = fmaf(w, xb, accB[oy]);
            }
        }

        __syncthreads();   // readers done with buf[cur]; stage of r+1 drained
        cur ^= 1;
    }

    // store: 16 oy x float2 per thread (zeros where no coverage — matches ref)
    #pragma unroll
    for (int oy = 0; oy < 16; ++oy) {
        float* op = out + (((size_t)box * 32 + oy0 + oy) * 32 + ox) * CH + ch0 + cp * 2;
        *(float2*)op = make_float2(accA[oy], accB[oy]);
    }
}

extern "C" void kernel_launch(void* const* d_in, const int* in_sizes, int n_in,
                              void* d_out, int out_size, void* d_ws, size_t ws_size,
                              hipStream_t stream) {
    const float* fm    = (const float*)d_in[0];
    const float* boxes = (const float*)d_in[1];
    // d_in[2] = output_width (==32), hardcoded.

    float* wTab = (float*)d_ws;                                   // 2*512*32*33 f32 = 4.33 MB
    int*   meta = (int*)((char*)d_ws + (size_t)2 * NB * 32 * WSTRIDE * sizeof(float)); // 512 KB

    roi_weights<<<(NB * 2 * 32 + 255) / 256, 256, 0, stream>>>(boxes, wTab, meta);
    roi_sep3<<<NB * 8, 256, 0, stream>>>(fm, wTab, meta, (float*)d_out);
}